// Round 13
// baseline (124.878 us; speedup 1.0000x reference)
//
#include <hip/hip_runtime.h>
#include <math.h>

// img (8, 3, 1024, 2048) fp32 -> same-shape fp32 output.
// r11 champion + DEEPER SKEW: cross-wave data consumed 2 bodies after publish
// -> barrier only after odd bodies (20/chunk vs 39). Pipeline per body L:
//   load L+1 / grad L-3 / hmax L-5 / vmax L-6 / hmin L-8 / out L-9.
// Rings: img LDS 5-deep (write@L overwrites row L-5, read@L-2: >=1 barrier
// between always), edge slots 4-deep (publish@L slot L&3, consume@L+2).
#define Wd 2048
#define Hd 1024
#define BC 24
#define CH 32          // output rows per block chunk (y0 % 8 == 0)
#define NT 512         // 8 waves; lane owns 4 consecutive cols
#define NW 8
#define SROW (Wd + 8)  // LDS img row: col c at index c+4 (zero halo +-4)

__device__ __forceinline__ float4 f4s(float v) { return make_float4(v, v, v, v); }

// Exact-equivalent rewrite of the reference masking (verified r4-r12, absmax 0).
__device__ __forceinline__ float masked_grad1(float g1, float g2, float g3) {
    const float HALF_T     = (float)(0.5 / 1023.0);
    const float GRD_BOTTOM = (float)(1.0 / 1023.0);
    const float GRD_UP     = (float)(4.0 / 1023.0);
    const float THIRD      = (float)(1.0 / 3.0);
    float m  = (g1 + g2 + g3) * THIRD;
    float lo = m - HALF_T;
    float hi = m + HALF_T;
    float a  = fabsf(g1);
    bool keep = (g1 >= lo) & (g1 <= hi) & (a >= GRD_BOTTOM) & (a <= GRD_UP);
    return keep ? g1 : 0.0f;
}

// UNSCALED gradmap row (K applied at store; exact, verified r12).
__device__ __forceinline__ float4 grad_row(float4 ce, float4 lf, float4 rt,
        float4 a1, float4 b1, float4 a2, float4 b2, float4 a3, float4 b3) {
    float gx0 = masked_grad1(ce.y - lf.w, ce.z - lf.z, ce.w - lf.y);
    float gx1 = masked_grad1(ce.z - ce.x, ce.w - lf.w, rt.x - lf.z);
    float gx2 = masked_grad1(ce.w - ce.y, rt.x - ce.x, rt.y - lf.w);
    float gx3 = masked_grad1(rt.x - ce.z, rt.y - ce.y, rt.z - ce.x);
    float gy0 = masked_grad1(a1.x - b1.x, a2.x - b2.x, a3.x - b3.x);
    float gy1 = masked_grad1(a1.y - b1.y, a2.y - b2.y, a3.y - b3.y);
    float gy2 = masked_grad1(a1.z - b1.z, a2.z - b2.z, a3.z - b3.z);
    float gy3 = masked_grad1(a1.w - b1.w, a2.w - b2.w, a3.w - b3.w);
    float4 g;
    g.x = fmaxf(fabsf(gx0), fabsf(gy0));
    g.y = fmaxf(fabsf(gx1), fabsf(gy1));
    g.z = fmaxf(fabsf(gx2), fabsf(gy2));
    g.w = fmaxf(fabsf(gx3), fabsf(gy3));
    return g;
}

struct State {
    float4 im[8];          // img rows; row r lives in slot r&7
    float4 gp0, gp1;       // grad rows L-5, L-4 entering body L
    float4 h0, h1;         // hmax rows L-7, L-6 entering body L
    float4 vm0, vm1;       // vmax rows L-8, L-7 entering body L
    float4 n0, n1;         // hmin rows L-10, L-9 entering body L
};

// LDS-visibility barrier WITHOUT the vmcnt(0) drain __syncthreads adds.
__device__ __forceinline__ void row_barrier() {
    asm volatile("s_waitcnt lgkmcnt(0)" ::: "memory");
    __builtin_amdgcn_s_barrier();
    asm volatile("" ::: "memory");
}

// One row, LM8 == L & 7 compile-time (y0 % 8 == 0). Barrier only after odd
// bodies. ws/rs = wave-uniform mod-5 LDS img ring slots (row L / row L-3).
template<int LM8, bool RE, bool STORE>
__device__ __forceinline__ void row_body(int L, State& S,
        const float* __restrict__ ip, float* __restrict__ op,
        int lane, int wv, int c0, float* s_img, int ws, int rs,
        float2 (*eL)[NW], float2 (*eR)[NW]) {
    constexpr int ESW = LM8 & 3;        // edge publish slot
    constexpr int ESR = (LM8 + 2) & 3;  // edge consume slot (published @ L-2)

    // cross-wave edge pairs {grad row L-5, vmax row L-8}, 2 bodies old
    float2 eRn = (wv > 0)      ? eR[ESR][wv - 1] : make_float2(-INFINITY, INFINITY);
    float2 eLn = (wv < NW - 1) ? eL[ESR][wv + 1] : make_float2(-INFINITY, INFINITY);

    // row L (in registers since last body) -> LDS ring slot ws
    float4 v = S.im[LM8];
    *(float4*)&s_img[ws * SROW + c0 + 4] = v;

    // issue load of row L+1 into its im slot (held row L-7, dead since L-1)
    {
        float4 nv = f4s(0.f);
        if (!RE || (L + 1) < Hd) nv = *(const float4*)(ip + (size_t)(L + 1) * Wd);
        S.im[(LM8 + 1) & 7] = nv;
    }

    // ---- gradient row L-3 (x-halo via LDS ring slot rs, >=2 barriers old) ----
    const float* sr = &s_img[rs * SROW];
    float4 lf = *(const float4*)&sr[c0];       // cols c0-4..c0-1 (zero halo)
    float4 rt = *(const float4*)&sr[c0 + 8];   // cols c0+4..c0+7
    float4 gv = grad_row(S.im[(LM8 + 5) & 7], lf, rt,                   // ce = L-3
                         S.im[(LM8 + 6) & 7], S.im[(LM8 + 4) & 7],      // L-2 - L-4
                         S.im[(LM8 + 7) & 7], S.im[(LM8 + 3) & 7],      // L-1 - L-5
                         v,                    S.im[(LM8 + 2) & 7]);    // L   - L-6

    // ---- hmax row L-5 (gp0 = grad L-5; edges 2 bodies old) ----
    float gl = __shfl_up(S.gp0.w, 1, 64);
    if (lane == 0)  gl = eRn.x;
    float gr = __shfl_down(S.gp0.x, 1, 64);
    if (lane == 63) gr = eLn.x;
    float4 hm;
    hm.x = fmaxf(fmaxf(gl,      S.gp0.x), S.gp0.y);
    hm.y = fmaxf(fmaxf(S.gp0.x, S.gp0.y), S.gp0.z);
    hm.z = fmaxf(fmaxf(S.gp0.y, S.gp0.z), S.gp0.w);
    hm.w = fmaxf(fmaxf(S.gp0.z, S.gp0.w), gr);
    if (RE) { if ((unsigned)(L - 5) >= (unsigned)Hd) hm = f4s(-INFINITY); }

    // ---- vmax row L-6 = max(hmax L-7, L-6, L-5) ----
    float4 vm;
    vm.x = fmaxf(fmaxf(S.h0.x, S.h1.x), hm.x);
    vm.y = fmaxf(fmaxf(S.h0.y, S.h1.y), hm.y);
    vm.z = fmaxf(fmaxf(S.h0.z, S.h1.z), hm.z);
    vm.w = fmaxf(fmaxf(S.h0.w, S.h1.w), hm.w);
    if (RE) { if ((unsigned)(L - 6) >= (unsigned)Hd) vm = f4s(INFINITY); }

    // ---- hmin row L-8 (vm0 = vmax L-8; edges 2 bodies old) ----
    float vl  = __shfl_up(S.vm0.w, 1, 64);
    if (lane == 0)  vl = eRn.y;
    float vr_ = __shfl_down(S.vm0.x, 1, 64);
    if (lane == 63) vr_ = eLn.y;
    float4 hn;
    hn.x = fminf(fminf(vl,       S.vm0.x), S.vm0.y);
    hn.y = fminf(fminf(S.vm0.x,  S.vm0.y), S.vm0.z);
    hn.z = fminf(fminf(S.vm0.y,  S.vm0.z), S.vm0.w);
    hn.w = fminf(fminf(S.vm0.z,  S.vm0.w), vr_);

    // ---- out row L-9 = min(hmin L-10, L-9, L-8), deferred K ----
    if (STORE) {
        const float K = 255.75f;  // 1023/4 exact
        float4 o;
        o.x = fminf(fminf(S.n0.x, S.n1.x), hn.x) * K;
        o.y = fminf(fminf(S.n0.y, S.n1.y), hn.y) * K;
        o.z = fminf(fminf(S.n0.z, S.n1.z), hn.z) * K;
        o.w = fminf(fminf(S.n0.w, S.n1.w), hn.w) * K;
        *(float4*)(op + (size_t)(L - 9) * Wd) = o;
    }

    // ---- ring updates (renames under unroll) ----
    S.h0 = S.h1;  S.h1 = hm;
    S.n0 = S.n1;  S.n1 = hn;
    S.gp0 = S.gp1; S.gp1 = gv;
    S.vm0 = S.vm1; S.vm1 = vm;

    // ---- edge publishes into slot ESW; consumed at body L+2 ----
    if (lane == 0)  eL[ESW][wv] = make_float2(gv.x, vm.x);
    if (lane == 63) eR[ESW][wv] = make_float2(gv.w, vm.w);

    if constexpr ((LM8 & 1) == 1) row_barrier();   // barrier after ODD bodies only
}

#define BODY(LM8v, Lv, STOREv)                                                   \
    row_body<LM8v, RE, STOREv>(Lv, S, ip, op, lane, wv, c0, s_img, ws, rs, eL, eR); \
    ws = (ws == 4) ? 0 : ws + 1;                                                  \
    rs = (rs == 4) ? 0 : rs + 1;

template<bool RE>
__device__ __forceinline__ void sweep(
        const float* __restrict__ ip, float* __restrict__ op, int y0,
        int tid, int lane, int wv, int c0,
        float* s_img, float2 (*eL)[NW], float2 (*eR)[NW]) {
    // constant zero halo columns for the 5 LDS img ring rows
    if (tid < 40) {
        int r = tid >> 3, j = tid & 7;
        int col = (j < 4) ? j : (Wd + j);
        s_img[r * SROW + col] = 0.0f;
    }
    // hygiene init of all 4 edge slots (feeds only never-stored rows)
    if (tid >= 64 && tid < 64 + 4 * NW) {
        int p = (tid - 64) >> 3, w = (tid - 64) & 7;
        eL[p][w] = make_float2(-INFINITY, INFINITY);
        eR[p][w] = make_float2(-INFINITY, INFINITY);
    }

    State S;
    S.gp0 = S.gp1 = f4s(0.f);
    S.h0 = S.h1 = f4s(-INFINITY);
    S.vm0 = S.vm1 = f4s(INFINITY);
    S.n0 = S.n1 = f4s(INFINITY);

    // ---- prime: rows y0-6..y0-1 -> im slots 2..7; rows y0-3..y0-1 -> LDS
    //      ring slots 2,3,4 (slot(row) = (row - y0) mod 5) ----
    #pragma unroll
    for (int r = 0; r < 6; ++r) {
        int row = y0 - 6 + r;
        float4 v = f4s(0.f);
        if (!RE || row >= 0) v = *(const float4*)(ip + (size_t)row * Wd);
        S.im[(r + 2) & 7] = v;
        if (r >= 3) *(float4*)&s_img[(r - 1) * SROW + c0 + 4] = v;  // slots 2,3,4
    }
    S.im[0] = *(const float4*)(ip + (size_t)y0 * Wd);  // row y0
    S.im[1] = f4s(0.f);
    __syncthreads();

    int ws = 0, rs = 2;   // body y0: write row y0 -> slot 0, read row y0-3 -> slot 2

    // ---- warm-up: 9 bodies, no store (fills all rings with real data) ----
    BODY(0, y0 + 0, false)
    BODY(1, y0 + 1, false)
    BODY(2, y0 + 2, false)
    BODY(3, y0 + 3, false)
    BODY(4, y0 + 4, false)
    BODY(5, y0 + 5, false)
    BODY(6, y0 + 6, false)
    BODY(7, y0 + 7, false)
    BODY(0, y0 + 8, false)

    // ---- steady: 32 store bodies (out rows y0 .. y0+31) ----
    #pragma unroll 1
    for (int jj = 0; jj < 4; ++jj) {
        const int Lb = y0 + 9 + jj * 8;   // (Lb - y0) % 8 == 1
        BODY(1, Lb + 0, true)
        BODY(2, Lb + 1, true)
        BODY(3, Lb + 2, true)
        BODY(4, Lb + 3, true)
        BODY(5, Lb + 4, true)
        BODY(6, Lb + 5, true)
        BODY(7, Lb + 6, true)
        BODY(0, Lb + 7, true)
    }
}

// 2nd arg = min BLOCKS per CU (r9/r10 decode): 3 blocks -> VGPR cap 84.
__global__ __launch_bounds__(NT, 3) void gradmap_skew2_kernel(
        const float* __restrict__ img, float* __restrict__ out) {
    const int plane = blockIdx.y;
    const int y0 = blockIdx.x * CH;
    const int tid = threadIdx.x;
    const int lane = tid & 63;
    const int wv = tid >> 6;
    const int c0 = tid << 2;
    const float* ip = img + (size_t)plane * Hd * Wd + c0;
    float*       op = out + (size_t)plane * Hd * Wd + c0;

    __shared__ float s_img[5 * SROW];            // 5-deep img ring (41 KB)
    __shared__ float2 s_eL[4][NW], s_eR[4][NW];  // 4-deep {grad, vmax} edges

    if (blockIdx.x == 0 || blockIdx.x == gridDim.x - 1)
        sweep<true >(ip, op, y0, tid, lane, wv, c0, s_img, s_eL, s_eR);
    else
        sweep<false>(ip, op, y0, tid, lane, wv, c0, s_img, s_eL, s_eR);
}

extern "C" void kernel_launch(void* const* d_in, const int* in_sizes, int n_in,
                              void* d_out, int out_size, void* d_ws, size_t ws_size,
                              hipStream_t stream) {
    const float* img = (const float*)d_in[0];
    float* out = (float*)d_out;
    dim3 grid(Hd / CH, BC);   // 32 x 24 = 768 blocks = 3/CU, balanced
    dim3 block(NT);
    gradmap_skew2_kernel<<<grid, block, 0, stream>>>(img, out);
}